// Round 9
// baseline (8751.588 us; speedup 1.0000x reference)
//
#include <hip/hip_runtime.h>
#include <hip/hip_bf16.h>
#include <math.h>

#define B_  256
#define T_  1024
#define S_  8
#define H_  256
#define L_  32
#define RH_ 32
#define NC  16
#define CB  16
#define MB  16
#define NR  16
#define TPB 256  // w0=layer0(t), w1=layer1 x-side(t-2), w2=layer1 h-side(t-2), w3=LN/dt(t+1)
#define FH  (B_*H_)
#define NPL 4    // h planes (step & 3); 8-bit tag disambiguates (alias period 128 >> lag)

typedef __attribute__((ext_vector_type(8))) short bf16x8;
typedef __attribute__((ext_vector_type(4))) float f32x4;
typedef __attribute__((ext_vector_type(4))) unsigned int uint4v;
typedef unsigned long long ull;
typedef unsigned int uint;

#define L2E 1.4426950408889634f

__device__ __forceinline__ void split_bf16(float v, short& hi, short& lo) {
    unsigned ub = __float_as_uint(v);
    float hf = __uint_as_float(ub & 0xffff0000u);
    hi = (short)(ub >> 16);
    lo = (short)(__float_as_uint(v - hf) >> 16);
}
__device__ __forceinline__ float fsigmoid(float a) {
    return __builtin_amdgcn_rcpf(1.f + __builtin_amdgcn_exp2f(-a * L2E));
}
__device__ __forceinline__ float ftanh(float a) {
    float e = __builtin_amdgcn_exp2f(a * (2.f * L2E));
    return 1.f - 2.f * __builtin_amdgcn_rcpf(e + 1.f);
}
__device__ __forceinline__ float fexpneg(float y) {
    return __builtin_amdgcn_exp2f(-y * L2E);
}
// tagged word = ((f32bits + 0x80) & 0xFFFFFF00) | tag8, tag = (step&127)+1 (never 0)
__device__ __forceinline__ uint tag_of(int step) { return (uint)((step & 127) + 1); }
__device__ __forceinline__ uint pack_h(float v, uint tg) {
    return ((__float_as_uint(v) + 0x80u) & 0xFFFFFF00u) | tg;
}
__device__ __forceinline__ float val_of(uint u) { return __uint_as_float(u & 0xFFFFFF00u); }

// ---- coherence-point ops (sc0 sc1) — R5-proven safe cross-XCD ----
__device__ __forceinline__ void st_u32(uint* p, uint v) {
    asm volatile("global_store_dword %0, %1, off sc0 sc1" :: "v"(p), "v"(v) : "memory");
}
template<int OFS> __device__ __forceinline__ void ld16(uint4v& r, const uint* base) {
    asm volatile("global_load_dwordx4 %0, %1, off offset:%c2 sc0 sc1"
                 : "=v"(r) : "v"(base), "i"(OFS) : "memory");
}
__device__ __forceinline__ uint ld_u32nc(const uint* p) {
    uint r;
    asm volatile("global_load_dword %0, %1, off sc0 sc1" : "=v"(r) : "v"(p) : "memory");
    return r;
}
template<int N>
__device__ __forceinline__ void guard4(uint4v& a, uint4v& b, uint4v& c, uint4v& d) {
    asm volatile("s_waitcnt vmcnt(%c4)"
                 : "+v"(a), "+v"(b), "+v"(c), "+v"(d) : "i"(N) : "memory");
}
__device__ __forceinline__ void tie2(uint& a, uint& b) {
    asm volatile("" : "+v"(a), "+v"(b));
}

#define TCHK(d) (((d.x & 255u) == tg) & ((d.y & 255u) == tg) & \
                 ((d.z & 255u) == tg) & ((d.w & 255u) == tg))

__global__ void __launch_bounds__(TPB, 1)
liquid_cfc_v9(const float* __restrict__ xs, const float* __restrict__ tstamp,
              const float* __restrict__ ln_g, const float* __restrict__ ln_b,
              const float* __restrict__ bb_w0, const float* __restrict__ bb_b0,
              const float* __restrict__ gx_w0, const float* __restrict__ gx_b0,
              const float* __restrict__ gh_w0, const float* __restrict__ gb0,
              const float* __restrict__ lt0,
              const float* __restrict__ bb_w1, const float* __restrict__ bb_b1,
              const float* __restrict__ gx_w1, const float* __restrict__ gx_b1,
              const float* __restrict__ gh_w1, const float* __restrict__ gb1,
              const float* __restrict__ lt1,
              const float* __restrict__ lp_w, const float* __restrict__ lp_b,
              const float* __restrict__ r1_w, const float* __restrict__ r1_b,
              const float* __restrict__ r2_w, const float* __restrict__ r2_b,
              float* __restrict__ out,
              uint* h0pk, uint* h1pk,                 // [NPL][B][H] tagged, fragment order
              uint* prog0, uint* prog1, uint* prog2,  // [NC][32] progress (128B/cluster)
              ull*  latg)
{
    const int tid  = threadIdx.x, lane = tid & 63, wid = tid >> 6;
    const int blk  = blockIdx.x,  c = blk >> 4,    j  = blk & 15;
    const int b0   = c * MB,      r0 = j * NR;
    const int n    = lane & 15,   quad = lane >> 4;

    __shared__ float s_xn[4][16][8];
    __shared__ float s_dt[8][16];
    __shared__ float s_gx0[16][8], s_bb0x[16][8];
    __shared__ float s_bg0[16], s_bf0[16], s_sp0[16];
    __shared__ float s_bg1[16], s_bf1[16], s_sp1[16];
    __shared__ float s_pg[2][16][16], s_pf[2][16][16];

    if (tid < 16) {
        s_bg0[tid] = gx_b0[r0+tid] + gb0[r0+tid];
        s_bf0[tid] = bb_b0[r0+tid];
        s_sp0[tid] = log1pf(expf(lt0[r0+tid]));
        s_bg1[tid] = gx_b1[r0+tid] + gb1[r0+tid];
        s_bf1[tid] = bb_b1[r0+tid];
        s_sp1[tid] = log1pf(expf(lt1[r0+tid]));
    }
    if (tid < 128) {
        int r = tid >> 3, s = tid & 7;
        s_gx0[r][s]  = gx_w0[(r0+r)*S_ + s];
        s_bb0x[r][s] = bb_w0[(r0+r)*(S_+H_) + s];
    }

    // weight B-fragments (bf16 hi/lo) per wave role
    bf16x8 whi[2][8], wlo[2][8];
    if (wid < 3) {
        const float* base[2]; int st[2], of[2];
        if (wid == 0)      { base[0]=gh_w0; st[0]=H_; of[0]=0;  base[1]=bb_w0; st[1]=S_+H_; of[1]=S_; }
        else if (wid == 1) { base[0]=gx_w1; st[0]=H_; of[0]=0;  base[1]=bb_w1; st[1]=2*H_;  of[1]=0;  }
        else               { base[0]=gh_w1; st[0]=H_; of[0]=0;  base[1]=bb_w1; st[1]=2*H_;  of[1]=H_; }
        int row = r0 + n;
        for (int mt = 0; mt < 2; ++mt) {
            const float* bp = base[mt] + (size_t)row * st[mt] + of[mt];
            for (int kb = 0; kb < 8; ++kb) {
                const float* sp = bp + kb*32 + quad*8;
                #pragma unroll
                for (int jj = 0; jj < 8; ++jj) {
                    short h_, l_;
                    split_bf16(sp[jj], h_, l_);
                    whi[mt][kb][jj] = h_; wlo[mt][kb][jj] = l_;
                }
            }
        }
    }
    float lngv[8] = {0,0,0,0,0,0,0,0}, lnbv[8] = {0,0,0,0,0,0,0,0}, tsPrev = 0.f;
    if (wid == 3 && lane < 16) {
        #pragma unroll
        for (int s = 0; s < 8; ++s) { lngv[s] = ln_g[s]; lnbv[s] = ln_b[s]; }
        int m = lane;
        const float* xp = xs + (size_t)(b0+m) * T_ * S_;
        float v[8]; float mu = 0.f;
        #pragma unroll
        for (int s = 0; s < 8; ++s) { v[s] = xp[s]; mu += v[s]; }
        mu *= 0.125f;
        float var = 0.f;
        #pragma unroll
        for (int s = 0; s < 8; ++s) { float d = v[s] - mu; var += d * d; }
        var *= 0.125f;
        float rstd = rsqrtf(var + 1e-5f);
        #pragma unroll
        for (int s = 0; s < 8; ++s) s_xn[0][m][s] = (v[s] - mu) * rstd * lngv[s] + lnbv[s];
        s_dt[0][m] = 1.0f;
        tsPrev = tstamp[(size_t)(b0+m) * T_];
    }
    float h0own[4] = {0.f,0.f,0.f,0.f};
    float h1own[4] = {0.f,0.f,0.f,0.f};
    const uint sidx = (uint)((((j*2 + (n>>3)) & 3) << 6) | ((j>>1) << 3) | (n & 7));
    __syncthreads();

    // ---- main loop: epoch t = layer0(step t) [w0] + layer1(step t-2) [w1,w2] ----
    for (int t = 0; t <= T_ + 1; ++t) {
        // w3: LN/dt for step t+1
        if (wid == 3 && lane < 16 && (t + 1) < T_) {
            int m = lane, tn = t + 1;
            const float* xp = xs + ((size_t)(b0+m) * T_ + tn) * S_;
            float v[8]; float mu = 0.f;
            #pragma unroll
            for (int s = 0; s < 8; ++s) { v[s] = xp[s]; mu += v[s]; }
            mu *= 0.125f;
            float var = 0.f;
            #pragma unroll
            for (int s = 0; s < 8; ++s) { float d = v[s] - mu; var += d * d; }
            var *= 0.125f;
            float rstd = rsqrtf(var + 1e-5f);
            #pragma unroll
            for (int s = 0; s < 8; ++s) s_xn[tn & 3][m][s] = (v[s] - mu) * rstd * lngv[s] + lnbv[s];
            float ts = tstamp[(size_t)(b0+m) * T_ + tn];
            s_dt[tn & 7][m] = fmaxf(ts - tsPrev, 1e-6f);
            tsPrev = ts;
        }

        f32x4 accg = {0.f,0.f,0.f,0.f}, accf = {0.f,0.f,0.f,0.f};
        const bool act0 = (wid == 0) && (t < T_);
        const bool act12 = (wid == 1 || wid == 2) && (t >= 2);
        const int  s12 = t - 2;   // layer1 step

        if (act0 || act12) {
            f32x4 g1 = {0,0,0,0}, g2 = {0,0,0,0}, g3 = {0,0,0,0};
            f32x4 f1 = {0,0,0,0}, f2 = {0,0,0,0}, f3 = {0,0,0,0};
            if (wid == 0) {
                #pragma unroll
                for (int i = 0; i < 4; ++i) {
                    int m = quad*4 + i;
                    float ag = s_bg0[n], af = s_bf0[n];
                    #pragma unroll
                    for (int s = 0; s < 8; ++s) {
                        float xv = s_xn[t & 3][m][s];
                        ag += s_gx0[n][s] * xv;
                        af += s_bb0x[n][s] * xv;
                    }
                    g1[i] = ag; f1[i] = af;
                }
            } else if (wid == 2) {
                #pragma unroll
                for (int i = 0; i < 4; ++i) { g1[i] = s_bg1[n]; f1[i] = s_bf1[n]; }
            }

            // A source + tag + plane-overwrite gates (progress rides the load batch)
            int astep; const uint* aplane; bool doload; uint need0 = 0, need1 = 0;
            const uint *gl0 = 0, *gl1 = 0;
            if (wid == 0) {
                astep = t - 1; aplane = h0pk; doload = (t >= 1);
                if (t >= 4) {
                    need0 = (uint)(t - 2); gl0 = prog0 + c*32 + n;
                    need1 = (uint)(t - 3); gl1 = prog1 + c*32 + n;
                }
            } else if (wid == 1) {
                astep = s12; aplane = h0pk; doload = true;          // 2-epoch slack
            } else {
                astep = s12 - 1; aplane = h1pk; doload = (s12 >= 1);
                if (s12 >= 4) { need0 = (uint)(s12 - 2); gl0 = prog2 + c*32 + n; }
            }

            uint4v d0,d1,d2,d3,d4,d5,d6,d7,d8,d9,d10,d11,d12,d13,d14,d15;
            if (doload) {
                const uint tg = tag_of(astep);
                const uint* ab = aplane + (size_t)(astep & 3) * FH
                                 + (size_t)(b0+n) * H_ + quad*64;
                bool g0ok = (gl0 == 0), g1ok = (gl1 == 0);
                for (;;) {
                    ld16<0>(d0,ab);   ld16<16>(d1,ab);  ld16<32>(d2,ab);  ld16<48>(d3,ab);
                    ld16<64>(d4,ab);  ld16<80>(d5,ab);  ld16<96>(d6,ab);  ld16<112>(d7,ab);
                    ld16<128>(d8,ab); ld16<144>(d9,ab); ld16<160>(d10,ab);ld16<176>(d11,ab);
                    ld16<192>(d12,ab);ld16<208>(d13,ab);ld16<224>(d14,ab);ld16<240>(d15,ab);
                    uint pv0 = 0, pv1 = 0;
                    if (!g0ok) pv0 = ld_u32nc(gl0);
                    if (!g1ok) pv1 = ld_u32nc(gl1);
                    guard4<0>(d0,d1,d2,d3);   guard4<0>(d4,d5,d6,d7);
                    guard4<0>(d8,d9,d10,d11); guard4<0>(d12,d13,d14,d15);
                    tie2(pv0, pv1);
                    bool tok = TCHK(d0) & TCHK(d1) & TCHK(d2) & TCHK(d3)
                             & TCHK(d4) & TCHK(d5) & TCHK(d6) & TCHK(d7)
                             & TCHK(d8) & TCHK(d9) & TCHK(d10)& TCHK(d11)
                             & TCHK(d12)& TCHK(d13)& TCHK(d14)& TCHK(d15);
                    if (!g0ok) g0ok = (__ballot(pv0 >= need0) == ~0ull);
                    if (!g1ok) g1ok = (__ballot(pv1 >= need1) == ~0ull);
                    if ((__ballot(tok) == ~0ull) & g0ok & g1ok) break;
                }
                uint4v dd[16] = {d0,d1,d2,d3,d4,d5,d6,d7,d8,d9,d10,d11,d12,d13,d14,d15};
                #pragma unroll
                for (int kb = 0; kb < 8; ++kb) {
                    uint4v A = dd[kb*2], Bv = dd[kb*2+1];
                    union { uint u[4]; bf16x8 v; } hi_, lo_;
                    uint au[8] = {A.x,A.y,A.z,A.w,Bv.x,Bv.y,Bv.z,Bv.w};
                    #pragma unroll
                    for (int pr = 0; pr < 4; ++pr) {
                        uint a = au[pr*2], b = au[pr*2+1];
                        hi_.u[pr] = __builtin_amdgcn_perm(b, a, 0x07060302u);
                        float fa = __uint_as_float(a & 0xFFFFFF00u) - __uint_as_float(a & 0xFFFF0000u);
                        float fb = __uint_as_float(b & 0xFFFFFF00u) - __uint_as_float(b & 0xFFFF0000u);
                        lo_.u[pr] = __builtin_amdgcn_perm(__float_as_uint(fb), __float_as_uint(fa),
                                                          0x07060302u);
                    }
                    g1 = __builtin_amdgcn_mfma_f32_16x16x32_bf16(hi_.v, whi[0][kb], g1, 0,0,0);
                    g2 = __builtin_amdgcn_mfma_f32_16x16x32_bf16(lo_.v, whi[0][kb], g2, 0,0,0);
                    g3 = __builtin_amdgcn_mfma_f32_16x16x32_bf16(hi_.v, wlo[0][kb], g3, 0,0,0);
                    f1 = __builtin_amdgcn_mfma_f32_16x16x32_bf16(hi_.v, whi[1][kb], f1, 0,0,0);
                    f2 = __builtin_amdgcn_mfma_f32_16x16x32_bf16(lo_.v, whi[1][kb], f2, 0,0,0);
                    f3 = __builtin_amdgcn_mfma_f32_16x16x32_bf16(hi_.v, wlo[1][kb], f3, 0,0,0);
                }
            }
            accg = (g1 + g2) + g3;
            accf = (f1 + f2) + f3;
            if (wid == 1) {
                #pragma unroll
                for (int i = 0; i < 4; ++i) {
                    s_pg[t & 1][quad*4+i][n] = accg[i];
                    s_pf[t & 1][quad*4+i][n] = accf[i];
                }
            }
        }

        __syncthreads();

        if (act0) {       // publish h0(t) tagged
            const uint tgo = tag_of(t);
            #pragma unroll
            for (int i = 0; i < 4; ++i) {
                int m = quad*4 + i;
                float g   = fsigmoid(accg[i]);
                float f   = ftanh(accf[i]);
                float dec = fexpneg(s_dt[t & 7][m] * (s_sp0[n] + fabsf(g)));
                h0own[i]  = dec * h0own[i] + (1.f - dec) * f;
                st_u32(h0pk + (size_t)(t & 3)*FH + (size_t)(b0+m)*H_ + sidx,
                       pack_h(h0own[i], tgo));
            }
            if (lane == 0) st_u32(prog0 + c*32 + j, (uint)(t + 1));
        }
        if (wid == 1 && t >= 2 && lane == 0)
            st_u32(prog1 + c*32 + j, (uint)(s12 + 1));
        if (wid == 2 && t >= 2) {   // publish h1(s12) tagged
            const uint tgo = tag_of(s12);
            #pragma unroll
            for (int i = 0; i < 4; ++i) {
                int m = quad*4 + i;
                float g   = fsigmoid(accg[i] + s_pg[t & 1][m][n]);
                float f   = ftanh(accf[i] + s_pf[t & 1][m][n]);
                float dec = fexpneg(s_dt[s12 & 7][m] * (s_sp1[n] + fabsf(g)));
                h1own[i]  = dec * h1own[i] + (1.f - dec) * f;
                st_u32(h1pk + (size_t)(s12 & 3)*FH + (size_t)(b0+m)*H_ + sidx,
                       pack_h(h1own[i], tgo));
            }
            if (lane == 0) st_u32(prog2 + c*32 + j, (uint)(s12 + 1));
        }
    }

    // ---- heads (wave 0; lanes 32-63 duplicate 0-31 so ballots are full-wave) ----
    if (wid == 0) {
        int ll = lane & 31;
        int lb = ll >> 1, l = j*2 + (ll & 1);
        const uint tg = tag_of(T_ - 1);               // h1(T-1): plane (T_-1)&3, tag 128
        const uint* hb = h1pk + (size_t)((T_-1) & 3) * FH + (size_t)(b0+lb) * H_;
        float acc = lp_b[l];
        // FULL row = 256 dwords = 4 chunks of 64; per-chunk tag-polled (R8 bug: read 1 chunk only)
        for (int q = 0; q < 4; ++q) {
            const uint* cb = hb + q*64;
            uint4v d0,d1,d2,d3,d4,d5,d6,d7,d8,d9,d10,d11,d12,d13,d14,d15;
            for (;;) {
                ld16<0>(d0,cb);   ld16<16>(d1,cb);  ld16<32>(d2,cb);  ld16<48>(d3,cb);
                ld16<64>(d4,cb);  ld16<80>(d5,cb);  ld16<96>(d6,cb);  ld16<112>(d7,cb);
                ld16<128>(d8,cb); ld16<144>(d9,cb); ld16<160>(d10,cb);ld16<176>(d11,cb);
                ld16<192>(d12,cb);ld16<208>(d13,cb);ld16<224>(d14,cb);ld16<240>(d15,cb);
                guard4<0>(d0,d1,d2,d3);   guard4<0>(d4,d5,d6,d7);
                guard4<0>(d8,d9,d10,d11); guard4<0>(d12,d13,d14,d15);
                bool tok = TCHK(d0) & TCHK(d1) & TCHK(d2) & TCHK(d3)
                         & TCHK(d4) & TCHK(d5) & TCHK(d6) & TCHK(d7)
                         & TCHK(d8) & TCHK(d9) & TCHK(d10)& TCHK(d11)
                         & TCHK(d12)& TCHK(d13)& TCHK(d14)& TCHK(d15);
                if (__ballot(tok) == ~0ull) break;
            }
            uint4v dd[16] = {d0,d1,d2,d3,d4,d5,d6,d7,d8,d9,d10,d11,d12,d13,d14,d15};
            #pragma unroll
            for (int i2 = 0; i2 < 16; ++i2) {
                uint uu[4] = {dd[i2].x, dd[i2].y, dd[i2].z, dd[i2].w};
                #pragma unroll
                for (int k2 = 0; k2 < 4; ++k2) {
                    int s = q*64 + i2*4 + k2;
                    int col = ((s>>3)&7)*32 + (s>>6)*8 + (s&7);
                    acc += val_of(uu[k2]) * lp_w[l*H_ + col];
                }
            }
        }
        float lat = tanhf(acc);
        out[(b0+lb)*L_ + l] = lat;
        if (lane < 32)
            __hip_atomic_store(&latg[(b0+lb)*L_ + l], (1ull << 32) | (ull)__float_as_uint(lat),
                               __ATOMIC_RELAXED, __HIP_MEMORY_SCOPE_AGENT);

        if (j == 0 && lane < 16) {
            float latv[L_];
            #pragma unroll
            for (int lx = 0; lx < L_; ++lx) {
                ull v;
                do {
                    v = __hip_atomic_load(&latg[(b0+lane)*L_ + lx],
                                          __ATOMIC_RELAXED, __HIP_MEMORY_SCOPE_AGENT);
                } while ((uint)(v >> 32) != 1u);
                latv[lx] = __uint_as_float((uint)v);
            }
            float acc2 = r2_b[0];
            for (int j2 = 0; j2 < RH_; ++j2) {
                float z = r1_b[j2];
                #pragma unroll
                for (int lx = 0; lx < L_; ++lx) z += r1_w[j2*L_ + lx] * latv[lx];
                float hid = 0.5f * z * (1.f + erff(z * 0.70710678118654752f)); // exact GELU
                acc2 += r2_w[j2] * hid;
            }
            out[B_*L_ + b0 + lane] = 1.f / (1.f + expf(-acc2));
        }
    }
}

extern "C" void kernel_launch(void* const* d_in, const int* in_sizes, int n_in,
                              void* d_out, int out_size, void* d_ws, size_t ws_size,
                              hipStream_t stream) {
    (void)in_sizes; (void)n_in; (void)out_size; (void)ws_size;
    const float* xs     = (const float*)d_in[0];
    const float* tstamp = (const float*)d_in[1];
    const float* ln_g   = (const float*)d_in[2];
    const float* ln_b   = (const float*)d_in[3];
    const float* bb_w0  = (const float*)d_in[4];
    const float* bb_b0  = (const float*)d_in[5];
    const float* gx_w0  = (const float*)d_in[6];
    const float* gx_b0  = (const float*)d_in[7];
    const float* gh_w0  = (const float*)d_in[8];
    const float* gb0    = (const float*)d_in[9];
    const float* lt0    = (const float*)d_in[10];
    const float* bb_w1  = (const float*)d_in[11];
    const float* bb_b1  = (const float*)d_in[12];
    const float* gx_w1  = (const float*)d_in[13];
    const float* gx_b1  = (const float*)d_in[14];
    const float* gh_w1  = (const float*)d_in[15];
    const float* gb1    = (const float*)d_in[16];
    const float* lt1    = (const float*)d_in[17];
    const float* lp_w   = (const float*)d_in[18];
    const float* lp_b   = (const float*)d_in[19];
    const float* r1_w   = (const float*)d_in[20];
    const float* r1_b   = (const float*)d_in[21];
    const float* r2_w   = (const float*)d_in[22];
    const float* r2_b   = (const float*)d_in[23];

    // ws: h0pk 4 planes (1MB) | h1pk 4 planes (1MB) | prog0/1/2 (2KB each) | latg 16KB
    uint8_t* w = (uint8_t*)d_ws;
    uint* h0pk  = (uint*)w;
    uint* h1pk  = h0pk + NPL * FH;
    uint* prog0 = h1pk + NPL * FH;
    uint* prog1 = prog0 + NC * 32;
    uint* prog2 = prog1 + NC * 32;
    ull*  latg  = (ull*)(prog2 + NC * 32);
    size_t zero_bytes = (size_t)(2 * NPL * FH + 3 * NC * 32) * sizeof(uint)
                      + (size_t)B_ * L_ * sizeof(ull);

    // zero: plane tags start 0 (invalid; valid tags 1..128); progress 0; latg 0
    hipMemsetAsync(d_ws, 0, zero_bytes, stream);

    liquid_cfc_v9<<<dim3(NC * CB), dim3(TPB), 0, stream>>>(
        xs, tstamp, ln_g, ln_b,
        bb_w0, bb_b0, gx_w0, gx_b0, gh_w0, gb0, lt0,
        bb_w1, bb_b1, gx_w1, gx_b1, gh_w1, gb1, lt1,
        lp_w, lp_b, r1_w, r1_b, r2_w, r2_b,
        (float*)d_out, h0pk, h1pk, prog0, prog1, prog2, latg);
}